// Round 6
// baseline (500.991 us; speedup 1.0000x reference)
//
#include <hip/hip_runtime.h>
#include <hip/hip_bf16.h>
#include <math.h>

// IntegralTransform via bf16 MFMA (16x16x32), two kernels:
//  prep: per-NODE linear precompute. Layer-1 preact is linear in the concat:
//        z1 = A[j] + B[i],  A[j] = y_j*W1[0:3] + fy_j*W1[6:38]  (64-dim)
//        B[i] = y_i*W1[3:6] + b1 (computed in-wave, 24 fma).
//        prep writes A_tbl[N][64] bf16 (128B = 1 full line/row) and
//        g_tbl[N][32] = w_j*fy_j bf16 (64B). Per-edge random gather is now
//        192 useful B / 2 lines (was 80/2) and layer-1 GEMM+staging is gone.
//  main: persistent 1536 blocks x 4 waves (6 blocks/CU via 26.6KB LDS ->
//        24 waves/CU). One wave = one point (32 edges = 2 M=16 tiles).
//        h1 formed IN REGISTERS from gathered A + B broadcast -> layer-2
//        MFMA -> gelu -> col-permuted LDS round trip -> layer-3 MFMA ->
//        epilogue scale by g (LDS-staged) -> shfl segment-reduce.
// No __syncthreads in main: buffers per-wave; same-wave DS ops are in order.

typedef __attribute__((ext_vector_type(8))) short short8;
typedef __attribute__((ext_vector_type(4))) float floatx4;

__device__ __forceinline__ unsigned short bf16rne(float f) {
    unsigned int u = __float_as_uint(f);
    u += 0x7fffu + ((u >> 16) & 1u);
    return (unsigned short)(u >> 16);
}
__device__ __forceinline__ unsigned int pk2(float a, float b) {
    union { __hip_bfloat162 h; unsigned int u; } cv;
    cv.h = __float22bfloat162_rn(make_float2(a, b));
    return cv.u;
}
__device__ __forceinline__ float bf16f(unsigned short u) {
    return __uint_as_float(((unsigned int)u) << 16);
}
__device__ __forceinline__ float blo(unsigned int u) { return __uint_as_float(u << 16); }
__device__ __forceinline__ float bhi(unsigned int u) { return __uint_as_float(u & 0xffff0000u); }
// sigmoid-form gelu: x/(1+exp(-1.702x)); |err| <= ~0.02, threshold 3.1e-1.
__device__ __forceinline__ float gelu_fast(float x) {
    float e = __expf(-1.702f * x);
    return x * __builtin_amdgcn_rcpf(1.0f + e);
}

#define MFMA16(a, b, c) __builtin_amdgcn_mfma_f32_16x16x32_bf16(a, b, c, 0, 0, 0)

// ---------------- prep: A_tbl[N][64], g_tbl[N][32] (both bf16) ----------------
__global__ __launch_bounds__(256) void it_prep(
    const float* __restrict__ y, const float* __restrict__ fy,
    const float* __restrict__ wts, const float* __restrict__ W1,
    unsigned short* __restrict__ A_tbl, unsigned short* __restrict__ g_tbl,
    int n)
{
    const int j = blockIdx.x * 4 + (threadIdx.x >> 6);   // 4 nodes per block
    const int l = threadIdx.x & 63;
    if (j >= n) return;
    const float* fyr = fy + (long)j * 32;
    float acc = y[3 * j] * W1[l];
    acc = fmaf(y[3 * j + 1], W1[64 + l], acc);
    acc = fmaf(y[3 * j + 2], W1[128 + l], acc);
    #pragma unroll
    for (int c = 0; c < 32; ++c)
        acc = fmaf(fyr[c], W1[(6 + c) * 64 + l], acc);
    A_tbl[(long)j * 64 + l] = bf16rne(acc);
    if (l < 32) g_tbl[(long)j * 32 + l] = bf16rne(wts[j] * fyr[l]);
}

// ---------------- main kernel ----------------
__global__ __launch_bounds__(256, 6) void it_mfma(
    const unsigned short* __restrict__ A_tbl,
    const unsigned short* __restrict__ g_tbl,
    const float* __restrict__ y,
    const float* __restrict__ W1, const float* __restrict__ b1,
    const float* __restrict__ W2, const float* __restrict__ b2,
    const float* __restrict__ W3, const float* __restrict__ b3,
    const int* __restrict__ nbr,
    float* __restrict__ out, int npts)
{
    __shared__ unsigned short ldsB[4][32][72];   // h2 round trip, 4608 B/wave
    __shared__ unsigned short ldsG[4][32][32];   // g stage,       2048 B/wave

    const int lane = threadIdx.x & 63;
    const int wv   = threadIdx.x >> 6;
    const int quad = lane >> 4;
    const int c16  = lane & 15;
    const int l31  = lane & 31;
    const int wgid   = blockIdx.x * 4 + wv;
    const int nwaves = gridDim.x * 4;

    // ---- per-lane B-slice of W1 rows 3..5 + b1: l = kb*32 + 8*quad + jj ----
    float wb0[2][8], wb1[2][8], wb2[2][8], b1e[2][8];
    #pragma unroll
    for (int kb = 0; kb < 2; ++kb)
        #pragma unroll
        for (int jj = 0; jj < 8; ++jj) {
            int l = kb * 32 + quad * 8 + jj;
            wb0[kb][jj] = W1[3 * 64 + l];
            wb1[kb][jj] = W1[4 * 64 + l];
            wb2[kb][jj] = W1[5 * 64 + l];
            b1e[kb][jj] = b1[l];
        }

    // ---- W2 fragments (natural k order: h1 is in natural channel order) ----
    short8 w2f[2][4], w3f[2][2];
    #pragma unroll
    for (int kb = 0; kb < 2; ++kb)
        #pragma unroll
        for (int nb = 0; nb < 4; ++nb)
            #pragma unroll
            for (int jj = 0; jj < 8; ++jj) {
                int k = kb * 32 + quad * 8 + jj;
                w2f[kb][nb][jj] = (short)bf16rne(W2[k * 64 + nb * 16 + c16]);
            }
    // ---- W3 fragments (k un-permutes h2's col-permuted store) ----
    #pragma unroll
    for (int kb = 0; kb < 2; ++kb)
        #pragma unroll
        for (int nb = 0; nb < 2; ++nb)
            #pragma unroll
            for (int jj = 0; jj < 8; ++jj) {
                int kp = kb * 32 + quad * 8 + jj;
                int kl = (kp & 3) * 16 + (kp >> 2);     // logical h2 channel
                w3f[kb][nb][jj] = (short)bf16rne(W3[kl * 32 + nb * 16 + c16]);
            }
    float b2v[4], b3v0, b3v1;
    #pragma unroll
    for (int nb = 0; nb < 4; ++nb) b2v[nb] = b2[nb * 16 + c16];
    b3v0 = b3[c16]; b3v1 = b3[16 + c16];

    unsigned short (*bufB)[72] = ldsB[wv];
    unsigned short (*bufG)[32] = ldsG[wv];

    const floatx4 fz = {0.f, 0.f, 0.f, 0.f};

    if (wgid >= npts) return;
    int jA = nbr[wgid * 32 + l31];           // 1-deep nbr prefetch

    for (int p = wgid; p < npts; p += nwaves) {
        const int pu = __builtin_amdgcn_readfirstlane(p);
        const int jcur = jA;
        {   // prefetch next point's nbr row
            int pn = p + nwaves;
            if (pn < npts) jA = nbr[pn * 32 + l31];
        }

        // ---- g stage: 2 lanes per row, 32 B each ----
        {
            int gr = lane >> 1;
            int jg = __shfl(jcur, gr, 64);
            const uint4* gp = (const uint4*)(g_tbl + (long)jg * 32 + ((lane & 1) << 4));
            uint4 gv0 = gp[0], gv1 = gp[1];
            *(uint4*)&bufG[gr][(lane & 1) * 16]     = gv0;
            *(uint4*)&bufG[gr][(lane & 1) * 16 + 8] = gv1;
        }

        // ---- B[i] slice (wave-uniform y_i, per-lane channels) ----
        float yi0 = y[3 * pu], yi1 = y[3 * pu + 1], yi2 = y[3 * pu + 2];
        float Bv[2][8];
        #pragma unroll
        for (int kb = 0; kb < 2; ++kb)
            #pragma unroll
            for (int jj = 0; jj < 8; ++jj)
                Bv[kb][jj] = fmaf(yi2, wb2[kb][jj],
                             fmaf(yi1, wb1[kb][jj],
                             fmaf(yi0, wb0[kb][jj], b1e[kb][jj])));

        // ---- gather A, form h1 A-frags in registers (layer 1 is free) ----
        short8 af[2][2];                        // [tile][kb]
        #pragma unroll
        for (int t = 0; t < 2; ++t) {
            int jt = __shfl(jcur, t * 16 + c16, 64);
            const uint4* ap = (const uint4*)(A_tbl + (long)jt * 64 + quad * 8);
            uint4 a0 = ap[0];                   // channels kb=0: 8q..8q+7
            uint4 a1 = ap[4];                   // channels kb=1: 32+8q..+7
            #pragma unroll
            for (int kb = 0; kb < 2; ++kb) {
                uint4 av = kb ? a1 : a0;
                float z0 = gelu_fast(blo(av.x) + Bv[kb][0]);
                float z1 = gelu_fast(bhi(av.x) + Bv[kb][1]);
                float z2 = gelu_fast(blo(av.y) + Bv[kb][2]);
                float z3 = gelu_fast(bhi(av.y) + Bv[kb][3]);
                float z4 = gelu_fast(blo(av.z) + Bv[kb][4]);
                float z5 = gelu_fast(bhi(av.z) + Bv[kb][5]);
                float z6 = gelu_fast(blo(av.w) + Bv[kb][6]);
                float z7 = gelu_fast(bhi(av.w) + Bv[kb][7]);
                union { uint4 u; short8 s; } cv;
                cv.u = make_uint4(pk2(z0, z1), pk2(z2, z3), pk2(z4, z5), pk2(z6, z7));
                af[t][kb] = cv.s;
            }
        }

        // ---- layer 2 ----
        floatx4 acc[2][4];
        #pragma unroll
        for (int t = 0; t < 2; ++t)
            #pragma unroll
            for (int nb = 0; nb < 4; ++nb) {
                acc[t][nb] = MFMA16(af[t][0], w2f[0][nb], fz);
                acc[t][nb] = MFMA16(af[t][1], w2f[1][nb], acc[t][nb]);
            }
        #pragma unroll
        for (int t = 0; t < 2; ++t)
            #pragma unroll
            for (int r = 0; r < 4; ++r) {
                float g0 = gelu_fast(acc[t][0][r] + b2v[0]);
                float g1 = gelu_fast(acc[t][1][r] + b2v[1]);
                float g2 = gelu_fast(acc[t][2][r] + b2v[2]);
                float g3 = gelu_fast(acc[t][3][r] + b2v[3]);
                *(uint2*)&bufB[t * 16 + quad * 4 + r][4 * c16] =
                    make_uint2(pk2(g0, g1), pk2(g2, g3));
            }

        // ---- layer 3 ----
        short8 h0[2], h1[2];
        #pragma unroll
        for (int t = 0; t < 2; ++t) {
            const int arow = t * 16 + c16;
            h0[t] = *(const short8*)&bufB[arow][quad * 8];
            h1[t] = *(const short8*)&bufB[arow][32 + quad * 8];
        }
        floatx4 o[2][2];
        #pragma unroll
        for (int t = 0; t < 2; ++t)
            #pragma unroll
            for (int nb = 0; nb < 2; ++nb) {
                o[t][nb] = MFMA16(h0[t], w3f[0][nb], fz);
                o[t][nb] = MFMA16(h1[t], w3f[1][nb], o[t][nb]);
            }

        // ---- epilogue: (o + b3) * g[j] from LDS, row-accumulate ----
        float colsum0 = 0.f, colsum1 = 0.f;
        #pragma unroll
        for (int t = 0; t < 2; ++t)
            #pragma unroll
            for (int r = 0; r < 4; ++r) {
                const int orow = t * 16 + quad * 4 + r;
                float ga = bf16f(bufG[orow][c16]);
                float gb = bf16f(bufG[orow][16 + c16]);
                colsum0 = fmaf(o[t][0][r] + b3v0, ga, colsum0);
                colsum1 = fmaf(o[t][1][r] + b3v1, gb, colsum1);
            }

        colsum0 += __shfl_xor(colsum0, 16, 64);
        colsum0 += __shfl_xor(colsum0, 32, 64);
        colsum1 += __shfl_xor(colsum1, 16, 64);
        colsum1 += __shfl_xor(colsum1, 32, 64);
        if (lane < 32)
            out[pu * 32 + lane] = (lane < 16) ? colsum0 : colsum1;
    }
}

extern "C" void kernel_launch(void* const* d_in, const int* in_sizes, int n_in,
                              void* d_out, int out_size, void* d_ws, size_t ws_size,
                              hipStream_t stream) {
    const float* y  = (const float*)d_in[0];
    const float* fy = (const float*)d_in[1];
    const float* wt = (const float*)d_in[2];
    const float* W1 = (const float*)d_in[3];
    const float* b1 = (const float*)d_in[4];
    const float* W2 = (const float*)d_in[5];
    const float* b2 = (const float*)d_in[6];
    const float* W3 = (const float*)d_in[7];
    const float* b3 = (const float*)d_in[8];
    const int* nbr  = (const int*)d_in[9];
    const int E = in_sizes[9];
    const int npts = E >> 5;              // K = 32 fixed
    const int N    = in_sizes[0] / 3;     // nodes
    float* out = (float*)d_out;

    // ws: A_tbl N*128B (line-aligned rows), then g_tbl N*64B  (9.6 MB total)
    unsigned short* A_tbl = (unsigned short*)d_ws;
    unsigned short* g_tbl = (unsigned short*)((char*)d_ws + (size_t)N * 128);

    hipLaunchKernelGGL(it_prep, dim3((N + 3) / 4), dim3(256), 0, stream,
                       y, fy, wt, W1, A_tbl, g_tbl, N);
    // persistent: 1536 blocks x 4 waves; 26.6KB LDS -> 6 blocks/CU = 24 waves/CU
    hipLaunchKernelGGL(it_mfma, dim3(1536), dim3(256), 0, stream,
                       A_tbl, g_tbl, y, W1, b1, W2, b2, W3, b3, nbr, out, npts);
}

// Round 7
// 303.186 us; speedup vs baseline: 1.6524x; 1.6524x over previous
//
#include <hip/hip_runtime.h>
#include <hip/hip_bf16.h>
#include <math.h>

// IntegralTransform via bf16 MFMA (16x16x32), two kernels:
//  prep: per-NODE fused table row T[j] = [A[j] (64 bf16) | g[j] (32 bf16)],
//        192 B/row (exactly 2 cache lines, 64B-aligned base).
//        A[j] = y_j*W1[0:3] + fy_j*W1[6:38]   (layer-1 preact, j part)
//        g[j] = w_j * fy_j                     (epilogue scale)
//  main: persistent 1024 blocks x 4 waves (4 blocks/CU = 16 waves/CU --
//        deliberately throttled: rounds 4-6 showed the random gather is
//        bound at ~3.7 TB/s effective L2-miss bandwidth, and higher
//        occupancy/prefetch only inflate the miss footprint).
//        One wave = one point (32 edges = 2 M=16 tiles). Per point:
//        ONE gather stream (3 x 16B/lane/tile from T), h1 formed in
//        registers (z1 = A[j] + B[i], B[i] = y_i*W1[3:6]+b1 via 24 fma),
//        layer-2 MFMA -> gelu -> col-permuted LDS round trip -> layer-3
//        MFMA -> epilogue scale by g (LDS) -> shfl segment reduce.
// No __syncthreads in main: buffers per-wave; same-wave DS ops are in order.

typedef __attribute__((ext_vector_type(8))) short short8;
typedef __attribute__((ext_vector_type(4))) float floatx4;

__device__ __forceinline__ unsigned short bf16rne(float f) {
    unsigned int u = __float_as_uint(f);
    u += 0x7fffu + ((u >> 16) & 1u);
    return (unsigned short)(u >> 16);
}
__device__ __forceinline__ unsigned int pk2(float a, float b) {
    union { __hip_bfloat162 h; unsigned int u; } cv;
    cv.h = __float22bfloat162_rn(make_float2(a, b));
    return cv.u;
}
__device__ __forceinline__ float bf16f(unsigned short u) {
    return __uint_as_float(((unsigned int)u) << 16);
}
__device__ __forceinline__ float blo(unsigned int u) { return __uint_as_float(u << 16); }
__device__ __forceinline__ float bhi(unsigned int u) { return __uint_as_float(u & 0xffff0000u); }
// sigmoid-form gelu: x/(1+exp(-1.702x)); |err| <= ~0.02, threshold 3.1e-1.
__device__ __forceinline__ float gelu_fast(float x) {
    float e = __expf(-1.702f * x);
    return x * __builtin_amdgcn_rcpf(1.0f + e);
}

#define MFMA16(a, b, c) __builtin_amdgcn_mfma_f32_16x16x32_bf16(a, b, c, 0, 0, 0)

// ---------------- prep: fused T[N][96] bf16 ----------------
__global__ __launch_bounds__(256) void it_prep(
    const float* __restrict__ y, const float* __restrict__ fy,
    const float* __restrict__ wts, const float* __restrict__ W1,
    unsigned short* __restrict__ T, int n)
{
    const int j = blockIdx.x * 4 + (threadIdx.x >> 6);   // 1 wave per node
    const int l = threadIdx.x & 63;
    if (j >= n) return;
    const float* fyr = fy + (long)j * 32;
    float acc = y[3 * j] * W1[l];
    acc = fmaf(y[3 * j + 1], W1[64 + l], acc);
    acc = fmaf(y[3 * j + 2], W1[128 + l], acc);
    #pragma unroll
    for (int c = 0; c < 32; ++c)
        acc = fmaf(fyr[c], W1[(6 + c) * 64 + l], acc);
    unsigned short* row = T + (long)j * 96;
    row[l] = bf16rne(acc);
    if (l < 32) row[64 + l] = bf16rne(wts[j] * fyr[l]);
}

// ---------------- main kernel ----------------
__global__ __launch_bounds__(256, 4) void it_mfma(
    const unsigned short* __restrict__ T,
    const float* __restrict__ y,
    const float* __restrict__ W1, const float* __restrict__ b1,
    const float* __restrict__ W2, const float* __restrict__ b2,
    const float* __restrict__ W3, const float* __restrict__ b3,
    const int* __restrict__ nbr,
    float* __restrict__ out, int npts)
{
    __shared__ unsigned short ldsB[4][32][72];   // h2 round trip
    __shared__ unsigned short ldsG[4][32][32];   // g stage

    const int lane = threadIdx.x & 63;
    const int wv   = threadIdx.x >> 6;
    const int quad = lane >> 4;
    const int c16  = lane & 15;
    const int l31  = lane & 31;
    const int wgid   = blockIdx.x * 4 + wv;
    const int nwaves = gridDim.x * 4;

    // ---- per-lane B-slice of W1 rows 3..5 + b1: channel = kb*32 + 8*quad + jj ----
    float wb0[2][8], wb1[2][8], wb2[2][8], b1e[2][8];
    #pragma unroll
    for (int kb = 0; kb < 2; ++kb)
        #pragma unroll
        for (int jj = 0; jj < 8; ++jj) {
            int l = kb * 32 + quad * 8 + jj;
            wb0[kb][jj] = W1[3 * 64 + l];
            wb1[kb][jj] = W1[4 * 64 + l];
            wb2[kb][jj] = W1[5 * 64 + l];
            b1e[kb][jj] = b1[l];
        }

    // ---- W2 fragments (natural k order) ----
    short8 w2f[2][4], w3f[2][2];
    #pragma unroll
    for (int kb = 0; kb < 2; ++kb)
        #pragma unroll
        for (int nb = 0; nb < 4; ++nb)
            #pragma unroll
            for (int jj = 0; jj < 8; ++jj) {
                int k = kb * 32 + quad * 8 + jj;
                w2f[kb][nb][jj] = (short)bf16rne(W2[k * 64 + nb * 16 + c16]);
            }
    // ---- W3 fragments (k un-permutes h2's col-permuted store) ----
    #pragma unroll
    for (int kb = 0; kb < 2; ++kb)
        #pragma unroll
        for (int nb = 0; nb < 2; ++nb)
            #pragma unroll
            for (int jj = 0; jj < 8; ++jj) {
                int kp = kb * 32 + quad * 8 + jj;
                int kl = (kp & 3) * 16 + (kp >> 2);     // logical h2 channel
                w3f[kb][nb][jj] = (short)bf16rne(W3[kl * 32 + nb * 16 + c16]);
            }
    float b2v[4], b3v0, b3v1;
    #pragma unroll
    for (int nb = 0; nb < 4; ++nb) b2v[nb] = b2[nb * 16 + c16];
    b3v0 = b3[c16]; b3v1 = b3[16 + c16];

    unsigned short (*bufB)[72] = ldsB[wv];
    unsigned short (*bufG)[32] = ldsG[wv];

    const floatx4 fz = {0.f, 0.f, 0.f, 0.f};

    if (wgid >= npts) return;
    int jA = nbr[wgid * 32 + l31];           // 1-deep nbr prefetch (stream)

    for (int p = wgid; p < npts; p += nwaves) {
        const int pu = __builtin_amdgcn_readfirstlane(p);
        const int jcur = jA;
        {   // prefetch next point's nbr row
            int pn = p + nwaves;
            if (pn < npts) jA = nbr[pn * 32 + l31];
        }

        // ---- B[i] slice (wave-uniform y_i, per-lane channels) ----
        float yi0 = y[3 * pu], yi1 = y[3 * pu + 1], yi2 = y[3 * pu + 2];
        float Bv[2][8];
        #pragma unroll
        for (int kb = 0; kb < 2; ++kb)
            #pragma unroll
            for (int jj = 0; jj < 8; ++jj)
                Bv[kb][jj] = fmaf(yi2, wb2[kb][jj],
                             fmaf(yi1, wb1[kb][jj],
                             fmaf(yi0, wb0[kb][jj], b1e[kb][jj])));

        // ---- single gather stream: T row = [A | g], 3 x 16B per lane per tile ----
        short8 af[2][2];                        // h1 A-frags [tile][kb]
        #pragma unroll
        for (int t = 0; t < 2; ++t) {
            int jt = __shfl(jcur, t * 16 + c16, 64);
            const uint4* ap = (const uint4*)(T + (long)jt * 96 + quad * 8);
            uint4 a0 = ap[0];                   // A channels kb=0: 8q..8q+7
            uint4 a1 = ap[4];                   // A channels kb=1: 32+8q..+7
            uint4 gv = ap[8];                   // g channels 8q..8q+7
            *(uint4*)&bufG[t * 16 + c16][quad * 8] = gv;
            #pragma unroll
            for (int kb = 0; kb < 2; ++kb) {
                uint4 av = kb ? a1 : a0;
                float z0 = gelu_fast(blo(av.x) + Bv[kb][0]);
                float z1 = gelu_fast(bhi(av.x) + Bv[kb][1]);
                float z2 = gelu_fast(blo(av.y) + Bv[kb][2]);
                float z3 = gelu_fast(bhi(av.y) + Bv[kb][3]);
                float z4 = gelu_fast(blo(av.z) + Bv[kb][4]);
                float z5 = gelu_fast(bhi(av.z) + Bv[kb][5]);
                float z6 = gelu_fast(blo(av.w) + Bv[kb][6]);
                float z7 = gelu_fast(bhi(av.w) + Bv[kb][7]);
                union { uint4 u; short8 s; } cv;
                cv.u = make_uint4(pk2(z0, z1), pk2(z2, z3), pk2(z4, z5), pk2(z6, z7));
                af[t][kb] = cv.s;
            }
        }

        // ---- layer 2 ----
        floatx4 acc[2][4];
        #pragma unroll
        for (int t = 0; t < 2; ++t)
            #pragma unroll
            for (int nb = 0; nb < 4; ++nb) {
                acc[t][nb] = MFMA16(af[t][0], w2f[0][nb], fz);
                acc[t][nb] = MFMA16(af[t][1], w2f[1][nb], acc[t][nb]);
            }
        #pragma unroll
        for (int t = 0; t < 2; ++t)
            #pragma unroll
            for (int r = 0; r < 4; ++r) {
                float g0 = gelu_fast(acc[t][0][r] + b2v[0]);
                float g1 = gelu_fast(acc[t][1][r] + b2v[1]);
                float g2 = gelu_fast(acc[t][2][r] + b2v[2]);
                float g3 = gelu_fast(acc[t][3][r] + b2v[3]);
                *(uint2*)&bufB[t * 16 + quad * 4 + r][4 * c16] =
                    make_uint2(pk2(g0, g1), pk2(g2, g3));
            }

        // ---- layer 3 ----
        short8 h0[2], h1[2];
        #pragma unroll
        for (int t = 0; t < 2; ++t) {
            const int arow = t * 16 + c16;
            h0[t] = *(const short8*)&bufB[arow][quad * 8];
            h1[t] = *(const short8*)&bufB[arow][32 + quad * 8];
        }
        floatx4 o[2][2];
        #pragma unroll
        for (int t = 0; t < 2; ++t)
            #pragma unroll
            for (int nb = 0; nb < 2; ++nb) {
                o[t][nb] = MFMA16(h0[t], w3f[0][nb], fz);
                o[t][nb] = MFMA16(h1[t], w3f[1][nb], o[t][nb]);
            }

        // ---- epilogue: (o + b3) * g[j] from LDS, row-accumulate ----
        float colsum0 = 0.f, colsum1 = 0.f;
        #pragma unroll
        for (int t = 0; t < 2; ++t)
            #pragma unroll
            for (int r = 0; r < 4; ++r) {
                const int orow = t * 16 + quad * 4 + r;
                float ga = bf16f(bufG[orow][c16]);
                float gb = bf16f(bufG[orow][16 + c16]);
                colsum0 = fmaf(o[t][0][r] + b3v0, ga, colsum0);
                colsum1 = fmaf(o[t][1][r] + b3v1, gb, colsum1);
            }

        colsum0 += __shfl_xor(colsum0, 16, 64);
        colsum0 += __shfl_xor(colsum0, 32, 64);
        colsum1 += __shfl_xor(colsum1, 16, 64);
        colsum1 += __shfl_xor(colsum1, 32, 64);
        if (lane < 32)
            out[pu * 32 + lane] = (lane < 16) ? colsum0 : colsum1;
    }
}

extern "C" void kernel_launch(void* const* d_in, const int* in_sizes, int n_in,
                              void* d_out, int out_size, void* d_ws, size_t ws_size,
                              hipStream_t stream) {
    const float* y  = (const float*)d_in[0];
    const float* fy = (const float*)d_in[1];
    const float* wt = (const float*)d_in[2];
    const float* W1 = (const float*)d_in[3];
    const float* b1 = (const float*)d_in[4];
    const float* W2 = (const float*)d_in[5];
    const float* b2 = (const float*)d_in[6];
    const float* W3 = (const float*)d_in[7];
    const float* b3 = (const float*)d_in[8];
    const int* nbr  = (const int*)d_in[9];
    const int E = in_sizes[9];
    const int npts = E >> 5;              // K = 32 fixed
    const int N    = in_sizes[0] / 3;     // nodes
    float* out = (float*)d_out;

    unsigned short* T = (unsigned short*)d_ws;   // N * 192 B fused table

    hipLaunchKernelGGL(it_prep, dim3((N + 3) / 4), dim3(256), 0, stream,
                       y, fy, wt, W1, T, N);
    // persistent: 1024 blocks x 4 waves = 4 blocks/CU (residency throttle)
    hipLaunchKernelGGL(it_mfma, dim3(1024), dim3(256), 0, stream,
                       T, y, W1, b1, W2, b2, W3, b3, nbr, out, npts);
}